// Round 16
// baseline (101.972 us; speedup 1.0000x reference)
//
#include <hip/hip_runtime.h>
#include <math.h>

typedef unsigned short u16;
typedef unsigned int u32;
typedef unsigned long long u64;
typedef float v2f __attribute__((ext_vector_type(2)));

#define NSYN 37
#define NB   2048
#define KS   296
#define NIN  39
#define TSTEPS 2000
#define SFRAMES 200
#define HID 256
#define OUTC 39
#define NBLK 204          // LIN blocks alloc'd per chain (fw uses 200, bw 201, pad)

// ws layout (byte offsets, 16B aligned)
#define WS_WIT    0u          // float [2][39][2048] dense input weights (transposed)
#define WS_WSPK   638976u     // float [2][37][2048] spike-synapse weights
#define WS_OFFSPK 1245184u    // u16   [2][37][2048] spike LDS byte offsets
#define WS_CBIAS  1548288u    // float [2][2048]     raw bias
#define WS_BETA   1564672u    // float [2][2048]
#define WS_ALPHA  1581056u    // float [2][256]
#define WS_FRAMES 1583104u    // float [2][32][200][256]
#define WS_Y      14690304u   // float [200][32][39]
#define WS_LINH   15688704u   // u16/fp16 [64 chains][204 blocks][2048] NATURAL branch order
#define WS_FLAG   69166080u   // u32: 0 = whole sequence certified silent

#define VMW0() asm volatile("s_waitcnt vmcnt(0)" ::: "memory")

// ---------------------------------------------------------------- setup ----
__global__ __launch_bounds__(256) void build_tables(
    const float* __restrict__ w_fw, const float* __restrict__ b_fw,
    const float* __restrict__ tau_n_fw, const float* __restrict__ mask_fw,
    const float* __restrict__ w_bw, const float* __restrict__ b_bw,
    const float* __restrict__ tau_n_bw, const float* __restrict__ mask_bw,
    const float* __restrict__ tau_m_fw, const float* __restrict__ tau_m_bw,
    float* __restrict__ WiT, float* __restrict__ Wspk, u16* __restrict__ OFFspk,
    float* __restrict__ CBIAS, float* __restrict__ BETA, float* __restrict__ ALPHA,
    u32* __restrict__ flagp, float* __restrict__ lossp)
{
  if (blockIdx.x == 0 && threadIdx.x == 0) { *flagp = 0u; *lossp = 0.0f; }
  const int row = blockIdx.x * 4 + (threadIdx.x >> 6);   // 0..4095
  const int l = threadIdx.x & 63;
  const int dir = row >> 11, r = row & (NB - 1);
  const float* w  = dir ? w_bw : w_fw;
  const float* mk = dir ? mask_bw : mask_fw;
  float* wit = WiT + (size_t)dir * (NIN * NB);
  float* wsp = Wspk + (size_t)dir * (NSYN * NB);
  u16*   osp = OFFspk + (size_t)dir * (NSYN * NB);
  const u64 ltm = (1ull << l) - 1ull;
  int sc = 0;
#pragma unroll
  for (int ch = 0; ch < 5; ++ch) {
    const int j = ch * 64 + l;
    const float m = (j < KS) ? mk[(size_t)r * KS + j] : 0.0f;
    const u64 bits = __ballot(m != 0.0f);
    const u64 sbits = (ch == 0) ? ((bits >> NIN) << NIN) : bits;  // entries j>=39
    if (ch == 0 && j < NIN) {
      wit[(size_t)j * NB + r] = (m != 0.0f) ? w[(size_t)r * KS + j] : 0.0f;
    } else if (m != 0.0f) {
      const int pos = sc + (int)__popcll(sbits & ltm);
      if (pos < NSYN) {
        wsp[(size_t)pos * NB + r] = w[(size_t)r * KS + j];
        osp[(size_t)pos * NB + r] = (u16)((j - NIN) * 4);
      }
    }
    sc += (int)__popcll(sbits);
  }
  for (int p = sc + l; p < NSYN; p += 64) {   // pad -> permanent-zero slot
    wsp[(size_t)p * NB + r] = 0.0f;
    osp[(size_t)p * NB + r] = (u16)(256 * 4);
  }
  if (l == 0) {
    const float* tn = dir ? tau_n_bw : tau_n_fw;
    const float* bb = dir ? b_bw : b_fw;
    BETA[dir * NB + r]  = 1.0f / (1.0f + expf(-tn[r]));
    CBIAS[dir * NB + r] = bb[r];
    if (r < HID) {
      const float* tm = dir ? tau_m_bw : tau_m_fw;
      ALPHA[dir * HID + r] = 1.0f / (1.0f + expf(-tm[r]));
    }
  }
}

// --------------------------------------------- per-frame input lin (fp16) ----
__global__ __launch_bounds__(512) void lin_gemm(
    const float* __restrict__ x, const float* __restrict__ WiT,
    const float* __restrict__ CBIAS, u16* __restrict__ LINH)
{
  const int bid = blockIdx.x;          // 0..1603
  const int cidx = bid >> 2, bg = bid & 3;
  const int dir = (cidx < 200) ? 0 : 1;
  const int c = (dir == 0) ? cidx : (cidx - 200);
  const int fr = (dir == 0) ? c : ((c == 0) ? 0 : 200 - c);
  const int b0 = bg * 8;
  const int t = threadIdx.x;

  __shared__ float xs[NIN * 8];        // xs[cc*8 + p]
  if (t < NIN * 8) {
    const int cc = t >> 3, p = t & 7;
    xs[t] = x[(size_t)(b0 + p) * (SFRAMES * NIN) + fr * NIN + cc];
  }
  __syncthreads();

  const float* wit = WiT + (size_t)dir * (NIN * NB) + t * 4;
  const float4 bv = *reinterpret_cast<const float4*>(CBIAS + dir * NB + t * 4);
  const float bias4[4] = {bv.x, bv.y, bv.z, bv.w};

  float acc[8][4];
#pragma unroll
  for (int p = 0; p < 8; ++p)
#pragma unroll
    for (int k = 0; k < 4; ++k) acc[p][k] = 0.0f;

#pragma unroll 3
  for (int cc = 0; cc < NIN; ++cc) {
    const float4 wv = *reinterpret_cast<const float4*>(wit + (size_t)cc * NB);
    const float4 s0 = *reinterpret_cast<const float4*>(&xs[cc * 8]);
    const float4 s1 = *reinterpret_cast<const float4*>(&xs[cc * 8 + 4]);
    const float sxa[8] = {s0.x, s0.y, s0.z, s0.w, s1.x, s1.y, s1.z, s1.w};
#pragma unroll
    for (int p = 0; p < 8; ++p) {
      acc[p][0] = fmaf(wv.x, sxa[p], acc[p][0]);
      acc[p][1] = fmaf(wv.y, sxa[p], acc[p][1]);
      acc[p][2] = fmaf(wv.z, sxa[p], acc[p][2]);
      acc[p][3] = fmaf(wv.w, sxa[p], acc[p][3]);
    }
  }

#pragma unroll
  for (int p = 0; p < 8; ++p) {
    u16* dst = LINH + ((size_t)(dir * 32 + b0 + p) * NBLK + c) * NB + t * 4;
    union { u16 h[4]; uint2 u; } pk;
#pragma unroll
    for (int k = 0; k < 4; ++k) {
      const _Float16 hv = (_Float16)(acc[p][k] + bias4[k]);
      pk.h[k] = *reinterpret_cast<const u16*>(&hv);
    }
    *reinterpret_cast<uint2*>(dst) = pk.u;
  }
}

// -------------------------------------------- parallel silent certificate ----
// One thread per (chain, neuron). BITWISE replay of the serial scan's fast
// path (same expression trees as snn_scan::fstep/commit below). Round-12
// structure: plain loads, 4 named regs, compiler-counted waits. New: SLC fold
// (mem = fmaf(al,mem,fmaf(om,esum,SLC)), SLC=om*Sl at commit), float lold
// (no re-cvt), and two-phase windows (all esums first, then the mem chain)
// for scheduler ILP. Values per op unchanged vs snn_scan's fast path.
__global__ __launch_bounds__(64) void cert_scan(
    const u16* __restrict__ LINH, const float* __restrict__ BETA,
    const float* __restrict__ ALPHA, u32* __restrict__ flag)
{
  const int bid = blockIdx.x;
  const int chain = bid >> 2;
  const int dir = chain >> 5;
  const int nrn = (bid & 3) * 64 + threadIdx.x;   // 0..255

  v2f e2[4], be2[4], lold[4];
  const v2f* bp = reinterpret_cast<const v2f*>(BETA + dir * NB + nrn * 8);
#pragma unroll
  for (int i = 0; i < 4; ++i) {
    be2[i] = bp[i];
    e2[i] = (v2f){0.f, 0.f};
    lold[i] = (v2f){0.f, 0.f};
  }
  const float al = ALPHA[dir * HID + nrn];
  const float om = 1.0f - al;

  float SLC = 0.0f, mem = 0.0f, mmax = -1e30f;

  const u16* ap = LINH + (size_t)chain * NBLK * NB + (size_t)nrn * 8;
  auto ld = [&](int k) {
    return *reinterpret_cast<const uint4*>(ap + (size_t)k * NB);
  };
  auto tree8 = [](const v2f v[4]) -> float {
    const v2f a = v[0] + v[1];
    const v2f b = v[2] + v[3];
    const v2f t = a + b;
    return t.x + t.y;
  };
  auto commit = [&](uint4 vn) {
    const _Float16* hn = reinterpret_cast<const _Float16*>(&vn);
    v2f ln2[4];
#pragma unroll
    for (int i = 0; i < 4; ++i) {
      const float fn0 = (float)hn[2 * i], fn1 = (float)hn[2 * i + 1];
      v2f dd; dd.x = lold[i].x - fn0; dd.y = lold[i].y - fn1;
      e2[i] += dd;
      ln2[i].x = fn0; ln2[i].y = fn1;
      lold[i] = ln2[i];
    }
    const float Sl = tree8(ln2);
    SLC = om * Sl;
  };
  // two-phase window: phase 1 advances e2 and records esums (e2-chain ILP);
  // phase 2 runs the serial mem/max chain. Same values as step-interleaved.
  auto win10 = [&]() {
    float es[10];
#pragma unroll
    for (int t = 0; t < 10; ++t) {
#pragma unroll
      for (int i = 0; i < 4; ++i) e2[i] *= be2[i];
      es[t] = tree8(e2);
    }
#pragma unroll
    for (int t = 0; t < 10; ++t) {
      mem = fmaf(al, mem, fmaf(om, es[t], SLC));
      mmax = fmaxf(mmax, mem);
    }
  };
  auto win9 = [&]() {
    float es[9];
#pragma unroll
    for (int t = 0; t < 9; ++t) {
#pragma unroll
      for (int i = 0; i < 4; ++i) e2[i] *= be2[i];
      es[t] = tree8(e2);
    }
#pragma unroll
    for (int t = 0; t < 9; ++t) {
      mem = fmaf(al, mem, fmaf(om, es[t], SLC));
      mmax = fmaxf(mmax, mem);
    }
  };
  auto fstep = [&]() {
#pragma unroll
    for (int i = 0; i < 4; ++i) e2[i] *= be2[i];
    const float esum = tree8(e2);
    mem = fmaf(al, mem, fmaf(om, esum, SLC));
    mmax = fmaxf(mmax, mem);
  };

  uint4 p0 = ld(0), p1 = ld(1), p2 = ld(2), p3 = ld(3);

  if (dir == 0) {
    // 200 windows of 10 steps; consumes c0..c199, issues up to c203 (pad)
#pragma unroll 1
    for (int w = 0; w < SFRAMES; w += 4) {
      commit(p0); p0 = ld(w + 4);
      win10();
      commit(p1); p1 = ld(w + 5);
      win10();
      commit(p2); p2 = ld(w + 6);
      win10();
      commit(p3); p3 = ld(w + 7);
      win10();
    }
  } else {
    // segments: c0 x1 step, c1..c199 x10 (as 1 fstep + commit + 9), c200 x(1+9)
    commit(p0); p0 = ld(4);       // c0
    fstep();
    commit(p1); p1 = ld(5);       // c1
    win9();
#pragma unroll 1
    for (int it = 0; it < 49; ++it) {    // commits c2..c197, issues c6..c201
      const int base = 6 + it * 4;
      fstep();
      commit(p2); p2 = ld(base);
      win9();
      fstep();
      commit(p3); p3 = ld(base + 1);
      win9();
      fstep();
      commit(p0); p0 = ld(base + 2);
      win9();
      fstep();
      commit(p1); p1 = ld(base + 3);
      win9();
    }
    // c198 (p2), c199 (p3), c200 (p0); c201 (p1) is pad, never consumed
    fstep();
    commit(p2);
    win9();
    fstep();
    commit(p3);
    win9();
    fstep();
    commit(p0);
    win9();
  }

  const bool fail = (mmax > 1.0f);
  if (__any(fail ? 1 : 0) && threadIdx.x == 0) atomicOr(flag, 1u);
}

// ------------------------------------------------------- recurrent core ----
__device__ __forceinline__ void gload_lds16(const void* g, void* l) {
  __builtin_amdgcn_global_load_lds(
      (const __attribute__((address_space(1))) void*)g,
      (__attribute__((address_space(3))) void*)l, 16, 0, 0);
}

// grid = 64 chains, block = 64 (ONE wave). Early-exits when certified silent.
// fstep here is bitwise-identical (per value) to cert_scan's fstep/win bodies.
__global__ __launch_bounds__(64, 1) void snn_scan(
    const u16* __restrict__ LINH, const float* __restrict__ Wspk,
    const u16* __restrict__ OFFspk, const float* __restrict__ BETA,
    const float* __restrict__ ALPHA, float* __restrict__ FRAMES,
    const u32* __restrict__ flag)
{
  if (*flag == 0u) return;     // certified silent: outputs produced downstream

  const int chain = blockIdx.x;
  const int dir = chain >> 5;
  const int l = threadIdx.x;

  __shared__ __align__(16) u16 ring[4][NB];   // lin fp16 4-slot ring
  __shared__ __align__(16) float spkbuf[260]; // spikes; slots 256..259 stay 0

  {
    const float4 z4 = {0.f, 0.f, 0.f, 0.f};
    *reinterpret_cast<float4*>(&spkbuf[l * 4]) = z4;
    if (l == 0) *reinterpret_cast<float4*>(&spkbuf[256]) = z4;
    const uint4 zu = {0u, 0u, 0u, 0u};
    uint4* zz = reinterpret_cast<uint4*>(&ring[3][l * 32]);   // lin(-1) = 0
    zz[0] = zu; zz[1] = zu; zz[2] = zu; zz[3] = zu;
  }

  v2f e2[4][4], be2[4][4];
  float SLC[4] = {0.f, 0.f, 0.f, 0.f};
  float mem[4] = {0.f, 0.f, 0.f, 0.f};
  float sp[4] = {0.f, 0.f, 0.f, 0.f};
  float al[4], om[4];
#pragma unroll
  for (int q = 0; q < 4; ++q) {
    const v2f* bp = reinterpret_cast<const v2f*>(BETA + dir * NB + l * 32 + q * 8);
#pragma unroll
    for (int i = 0; i < 4; ++i) { be2[q][i] = bp[i]; e2[q][i] = (v2f){0.f, 0.f}; }
    al[q] = ALPHA[dir * HID + l * 4 + q];
    om[q] = 1.0f - al[q];
  }

  const u16* LB = LINH + (size_t)chain * NBLK * NB;
#pragma unroll
  for (int i = 0; i < 4; ++i) {
    gload_lds16(LB + 0 * NB + i * 512 + l * 8, &ring[0][i * 512]);
    gload_lds16(LB + 1 * NB + i * 512 + l * 8, &ring[1][i * 512]);
  }

  const float* wsp = Wspk + (size_t)dir * (NSYN * NB) + l * 32;
  const u16*  ofp = OFFspk + (size_t)dir * (NSYN * NB) + l * 32;
  float* frow = FRAMES + (size_t)chain * (SFRAMES * HID) + l * 4;

  int F = 0, c = 0;
  float mmax[4], facc[4];
  float4 pend = {0.f, 0.f, 0.f, 0.f};

  auto tree8 = [](const v2f v[4]) -> float {
    const v2f a = v[0] + v[1];
    const v2f b = v[2] + v[3];
    const v2f t = a + b;
    return t.x + t.y;
  };

  auto commit = [&](bool dopref) {
    const int sn = c & 3, so = (c + 3) & 3;
#pragma unroll
    for (int q = 0; q < 4; ++q) {
      const uint4 vn = *reinterpret_cast<const uint4*>(&ring[sn][l * 32 + q * 8]);
      const uint4 vo = *reinterpret_cast<const uint4*>(&ring[so][l * 32 + q * 8]);
      const _Float16* hn = reinterpret_cast<const _Float16*>(&vn);
      const _Float16* ho = reinterpret_cast<const _Float16*>(&vo);
      v2f ln2[4];
#pragma unroll
      for (int i = 0; i < 4; ++i) {
        const float fn0 = (float)hn[2 * i], fn1 = (float)hn[2 * i + 1];
        v2f dd; dd.x = (float)ho[2 * i] - fn0; dd.y = (float)ho[2 * i + 1] - fn1;
        e2[q][i] += dd;
        ln2[i].x = fn0; ln2[i].y = fn1;
      }
      const float Sl = tree8(ln2);
      SLC[q] = om[q] * Sl;
    }
    if (dopref) {
      const u16* src = LB + (size_t)(c + 2) * NB;
      u16* dst = &ring[(c + 2) & 3][0];
#pragma unroll
      for (int i = 0; i < 4; ++i)
        gload_lds16(src + i * 512 + l * 8, dst + i * 512);
    }
    ++c;
  };

  auto fstep = [&]() {
#pragma unroll
    for (int q = 0; q < 4; ++q)
#pragma unroll
      for (int i = 0; i < 4; ++i) e2[q][i] *= be2[q][i];
#pragma unroll
    for (int q = 0; q < 4; ++q) {
      const float esum = tree8(e2[q]);
      mem[q] = fmaf(al[q], mem[q], fmaf(om[q], esum, SLC[q]));
      mmax[q] = fmaxf(mmax[q], mem[q]);
    }
  };

  auto sstep = [&]() {
    if (__builtin_expect(F, 0)) {       // spikes live: exact gather
      float scv[4][8];
#pragma unroll
      for (int q = 0; q < 4; ++q)
#pragma unroll
        for (int j = 0; j < 8; ++j) scv[q][j] = 0.0f;
      const char* kb = reinterpret_cast<const char*>(&spkbuf[0]);
#pragma unroll 1
      for (int s = 0; s < NSYN; ++s) {
#pragma unroll
        for (int q = 0; q < 4; ++q) {
          float wv[8];
          *reinterpret_cast<float4*>(&wv[0]) =
              *reinterpret_cast<const float4*>(wsp + (size_t)s * NB + q * 8);
          *reinterpret_cast<float4*>(&wv[4]) =
              *reinterpret_cast<const float4*>(wsp + (size_t)s * NB + q * 8 + 4);
          const uint4 ov = *reinterpret_cast<const uint4*>(ofp + (size_t)s * NB + q * 8);
          const u16* of = reinterpret_cast<const u16*>(&ov);
#pragma unroll
          for (int j = 0; j < 8; ++j)
            scv[q][j] += wv[j] * *reinterpret_cast<const float*>(kb + of[j]);
        }
      }
#pragma unroll
      for (int q = 0; q < 4; ++q)
#pragma unroll
        for (int i = 0; i < 4; ++i) {
          v2f sc2; sc2.x = scv[q][2 * i]; sc2.y = scv[q][2 * i + 1];
          const v2f one = {1.0f, 1.0f};
          e2[q][i] = be2[q][i] * e2[q][i] + (one - be2[q][i]) * sc2;
        }
    } else {                            // silent: identical to fstep core
#pragma unroll
      for (int q = 0; q < 4; ++q)
#pragma unroll
        for (int i = 0; i < 4; ++i) e2[q][i] *= be2[q][i];
    }
    float ssum = 0.0f;
#pragma unroll
    for (int q = 0; q < 4; ++q) {
      const float esum = tree8(e2[q]);
      const float g = fmaf(om[q], esum, SLC[q]);
      mem[q] = fmaf(al[q], mem[q], g - sp[q]);
      sp[q] = (mem[q] > 1.0f) ? 1.0f : 0.0f;
      facc[q] += sp[q];
      ssum += sp[q];
    }
    const float4 sv = {sp[0], sp[1], sp[2], sp[3]};
    *reinterpret_cast<float4*>(&spkbuf[l * 4]) = sv;
    F = __any(ssum > 0.0f);
  };

#pragma unroll 1
  for (int w = 0; w < SFRAMES; ++w) {
    v2f es[4][4]; float SLCs[4], mems_[4], sps[4];
#pragma unroll
    for (int q = 0; q < 4; ++q) {
#pragma unroll
      for (int i = 0; i < 4; ++i) es[q][i] = e2[q][i];
      SLCs[q] = SLC[q]; mems_[q] = mem[q]; sps[q] = sp[q];
    }
    const int cs = c;
    bool slow = (F != 0);
    bool prefed = false;

    if (!slow) {
      prefed = true;
      mmax[0] = mmax[1] = mmax[2] = mmax[3] = -1e30f;
      if (dir == 0) {
        VMW0(); commit(true);
        if (w) *reinterpret_cast<float4*>(frow + (w - 1) * HID) = pend;
#pragma unroll
        for (int t = 0; t < 10; ++t) fstep();
      } else {
        if (w == 0) { VMW0(); commit(true); }
        fstep();
        VMW0(); commit(true);
        if (w) *reinterpret_cast<float4*>(frow + (w - 1) * HID) = pend;
#pragma unroll
        for (int t = 0; t < 9; ++t) fstep();
      }
      const int viol = (mmax[0] > 1.0f) || (mmax[1] > 1.0f) ||
                       (mmax[2] > 1.0f) || (mmax[3] > 1.0f);
      slow = (__any(viol) != 0);
      if (!slow) {
        pend = (float4){0.f, 0.f, 0.f, 0.f};   // facc = 0 exactly
      } else {                                  // restore + redo
#pragma unroll
        for (int q = 0; q < 4; ++q) {
#pragma unroll
          for (int i = 0; i < 4; ++i) e2[q][i] = es[q][i];
          SLC[q] = SLCs[q]; mem[q] = mems_[q]; sp[q] = sps[q];
        }
        c = cs;
      }
    }
    if (slow) {
      facc[0] = facc[1] = facc[2] = facc[3] = 0.0f;
      if (dir == 0) {
        VMW0(); commit(!prefed);
        if (w) *reinterpret_cast<float4*>(frow + (w - 1) * HID) = pend;
#pragma unroll 1
        for (int t = 0; t < 10; ++t) sstep();
      } else {
        if (w == 0) { VMW0(); commit(!prefed); }
        sstep();
        VMW0(); commit(!prefed);
        if (w) *reinterpret_cast<float4*>(frow + (w - 1) * HID) = pend;
#pragma unroll 1
        for (int t = 0; t < 9; ++t) sstep();
      }
      pend = (float4){facc[0] * 0.1f, facc[1] * 0.1f, facc[2] * 0.1f, facc[3] * 0.1f};
    }
  }
  *reinterpret_cast<float4*>(frow + (SFRAMES - 1) * HID) = pend;
}

// ------------------------------------------------------------- readout ----
__global__ __launch_bounds__(256) void ro_matmul(
    const float* __restrict__ FRAMES, const float* __restrict__ w_ro,
    const float* __restrict__ b_ro, float* __restrict__ Y,
    const u32* __restrict__ flag)
{
  if (*flag == 0u) return;   // certified silent: ro_scan uses b_ro directly

  const int bid = blockIdx.x;
  const int s = bid >> 1, b0 = (bid & 1) * 16;
  __shared__ float rowc[16 * 132];
  __shared__ float wlds[48 * 132];
  const int bb = threadIdx.x >> 4;
  const int oc = threadIdx.x & 15;
  const int o1 = oc + 16, o2 = oc + 32;
  float a0 = 0.f, a1 = 0.f, a2 = 0.f;
  const bool u2 = (o2 < OUTC);

#pragma unroll 1
  for (int kc = 0; kc < 4; ++kc) {
    for (int i = threadIdx.x; i < 16 * 128; i += 256) {
      const int rb = i >> 7, kk = i & 127;
      float v;
      if (kc < 2)
        v = FRAMES[((size_t)(b0 + rb) * SFRAMES + s) * HID + kc * 128 + kk];
      else
        v = FRAMES[((size_t)(32 + b0 + rb) * SFRAMES + (199 - s)) * HID + (kc - 2) * 128 + kk];
      rowc[rb * 132 + kk] = v;
    }
    for (int i = threadIdx.x; i < OUTC * 128; i += 256) {
      const int o = i >> 7, kk = i & 127;
      wlds[o * 132 + kk] = w_ro[(size_t)o * 512 + kc * 128 + kk];
    }
    __syncthreads();

    const float* rp = &rowc[bb * 132];
    const float* w0 = &wlds[oc * 132];
    const float* w1 = &wlds[o1 * 132];
    const float* w2 = &wlds[o2 * 132];
#pragma unroll 8
    for (int kk = 0; kk < 128; kk += 4) {
      const float4 a  = *reinterpret_cast<const float4*>(rp + kk);
      const float4 v0 = *reinterpret_cast<const float4*>(w0 + kk);
      const float4 v1 = *reinterpret_cast<const float4*>(w1 + kk);
      const float4 v2 = *reinterpret_cast<const float4*>(w2 + kk);
      a0 = fmaf(a.x, v0.x, fmaf(a.y, v0.y, fmaf(a.z, v0.z, fmaf(a.w, v0.w, a0))));
      a1 = fmaf(a.x, v1.x, fmaf(a.y, v1.y, fmaf(a.z, v1.z, fmaf(a.w, v1.w, a1))));
      if (u2)
        a2 = fmaf(a.x, v2.x, fmaf(a.y, v2.y, fmaf(a.z, v2.z, fmaf(a.w, v2.w, a2))));
    }
    __syncthreads();
  }

  float* yp = Y + ((size_t)s * 32 + b0 + bb) * OUTC;
  yp[oc] = a0 + b_ro[oc];
  yp[o1] = a1 + b_ro[o1];
  if (u2) yp[o2] = a2 + b_ro[o2];
}

__global__ __launch_bounds__(256) void ro_scan(
    const float* __restrict__ Y, const float* __restrict__ tau_ro,
    const float* __restrict__ b_ro, const int* __restrict__ labels,
    float* __restrict__ out, const u32* __restrict__ flag)
{
  const int b = blockIdx.x;
  const int tid = threadIdx.x;
  __shared__ float buf[SFRAMES * 40];
  __shared__ float lsum[256];

  if (*flag == 0u) {
    if (tid < OUTC) {
      const float ar = 1.0f / (1.0f + expf(-tau_ro[tid]));
      const float omr = 1.0f - ar;
      const float z = b_ro[tid];
      float m = 0.0f;
#pragma unroll 4
      for (int s = 0; s < SFRAMES; ++s) {
        m = ar * m + omr * z;
        buf[s * 40 + tid] = m;
      }
    }
  } else {
    for (int i = tid; i < SFRAMES * OUTC; i += 256) {
      const int s = i / OUTC, o = i - s * OUTC;
      buf[s * 40 + o] = Y[((size_t)s * 32 + b) * OUTC + o];
    }
    __syncthreads();
    if (tid < OUTC) {
      const float ar = 1.0f / (1.0f + expf(-tau_ro[tid]));
      const float omr = 1.0f - ar;
      float m = 0.0f;
#pragma unroll 4
      for (int s = 0; s < SFRAMES; ++s) {
        m = ar * m + omr * buf[s * 40 + tid];
        buf[s * 40 + tid] = m;
      }
    }
  }
  __syncthreads();

  float nacc = 0.0f;
  for (int s = tid; s < SFRAMES; s += 256) {
    float mx = -1e30f;
    for (int j = 0; j < OUTC; ++j) mx = fmaxf(mx, buf[s * 40 + j]);
    float se = 0.0f;
    for (int j = 0; j < OUTC; ++j) se += expf(buf[s * 40 + j] - mx);
    const float lse = logf(se);
    float* op = out + ((size_t)s * 32 + b) * OUTC;
    for (int j = 0; j < OUTC; ++j) op[j] = buf[s * 40 + j] - mx - lse;
    const int lab = labels[b * SFRAMES + s];
    nacc += -(buf[s * 40 + lab] - mx - lse);
  }
  lsum[tid] = nacc;
  __syncthreads();
  for (int off = 128; off > 0; off >>= 1) {
    if (tid < off) lsum[tid] += lsum[tid + off];
    __syncthreads();
  }
  if (tid == 0) atomicAdd(out + SFRAMES * 32 * OUTC, lsum[0] * (1.0f / 32.0f));
}

// -------------------------------------------------------------- launch ----
extern "C" void kernel_launch(void* const* d_in, const int* in_sizes, int n_in,
                              void* d_out, int out_size, void* d_ws, size_t ws_size,
                              hipStream_t stream)
{
  const float* x        = (const float*)d_in[0];
  const int*   labels   = (const int*)d_in[1];
  const float* w_fw     = (const float*)d_in[2];
  const float* b_fw     = (const float*)d_in[3];
  const float* tau_m_fw = (const float*)d_in[4];
  const float* tau_n_fw = (const float*)d_in[5];
  const float* mask_fw  = (const float*)d_in[6];
  const float* w_bw     = (const float*)d_in[7];
  const float* b_bw     = (const float*)d_in[8];
  const float* tau_m_bw = (const float*)d_in[9];
  const float* tau_n_bw = (const float*)d_in[10];
  const float* mask_bw  = (const float*)d_in[11];
  const float* w_ro     = (const float*)d_in[12];
  const float* b_ro     = (const float*)d_in[13];
  const float* tau_m_ro = (const float*)d_in[14];
  float* out = (float*)d_out;

  char* ws = (char*)d_ws;
  float* WiT    = (float*)(ws + WS_WIT);
  float* Wspk   = (float*)(ws + WS_WSPK);
  u16*   OFFspk = (u16*)(ws + WS_OFFSPK);
  float* CBIAS  = (float*)(ws + WS_CBIAS);
  float* BETA   = (float*)(ws + WS_BETA);
  float* ALPHA  = (float*)(ws + WS_ALPHA);
  float* FRAMES = (float*)(ws + WS_FRAMES);
  float* Y      = (float*)(ws + WS_Y);
  u16*   LINH   = (u16*)(ws + WS_LINH);
  u32*   FLAG   = (u32*)(ws + WS_FLAG);

  build_tables<<<1024, 256, 0, stream>>>(w_fw, b_fw, tau_n_fw, mask_fw,
                                         w_bw, b_bw, tau_n_bw, mask_bw,
                                         tau_m_fw, tau_m_bw,
                                         WiT, Wspk, OFFspk, CBIAS, BETA, ALPHA,
                                         FLAG, out + SFRAMES * 32 * OUTC);
  lin_gemm<<<1604, 512, 0, stream>>>(x, WiT, CBIAS, LINH);
  cert_scan<<<256, 64, 0, stream>>>(LINH, BETA, ALPHA, FLAG);
  snn_scan<<<64, 64, 0, stream>>>(LINH, Wspk, OFFspk, BETA, ALPHA, FRAMES, FLAG);
  ro_matmul<<<2 * SFRAMES, 256, 0, stream>>>(FRAMES, w_ro, b_ro, Y, FLAG);
  ro_scan<<<32, 256, 0, stream>>>(Y, tau_m_ro, b_ro, labels, out, FLAG);
}

// Round 17
// 97.906 us; speedup vs baseline: 1.0415x; 1.0415x over previous
//
#include <hip/hip_runtime.h>
#include <math.h>

typedef unsigned short u16;
typedef unsigned int u32;
typedef unsigned long long u64;
typedef float v2f __attribute__((ext_vector_type(2)));

#define NSYN 37
#define NB   2048
#define KS   296
#define NIN  39
#define TSTEPS 2000
#define SFRAMES 200
#define HID 256
#define OUTC 39
#define NBLK 204          // LIN blocks alloc'd per chain (fw uses 200, bw 201, pad)

// ws layout (byte offsets, 16B aligned)
#define WS_WIT    0u          // float [2][39][2048] dense input weights (transposed)
#define WS_WSPK   638976u     // float [2][37][2048] spike-synapse weights
#define WS_OFFSPK 1245184u    // u16   [2][37][2048] spike LDS byte offsets
#define WS_CBIAS  1548288u    // float [2][2048]     raw bias
#define WS_BETA   1564672u    // float [2][2048]
#define WS_ALPHA  1581056u    // float [2][256]
#define WS_FRAMES 1583104u    // float [2][32][200][256]
#define WS_Y      14690304u   // float [200][32][39]
#define WS_LINH   15688704u   // u16/fp16 [64 chains][204 blocks][2048] NATURAL branch order
#define WS_FLAG   69166080u   // u32: 0 = whole sequence certified silent

#define VMW0() asm volatile("s_waitcnt vmcnt(0)" ::: "memory")

// ---------------------------------------------------------------- setup ----
__global__ __launch_bounds__(256) void build_tables(
    const float* __restrict__ w_fw, const float* __restrict__ b_fw,
    const float* __restrict__ tau_n_fw, const float* __restrict__ mask_fw,
    const float* __restrict__ w_bw, const float* __restrict__ b_bw,
    const float* __restrict__ tau_n_bw, const float* __restrict__ mask_bw,
    const float* __restrict__ tau_m_fw, const float* __restrict__ tau_m_bw,
    float* __restrict__ WiT, float* __restrict__ Wspk, u16* __restrict__ OFFspk,
    float* __restrict__ CBIAS, float* __restrict__ BETA, float* __restrict__ ALPHA,
    u32* __restrict__ flagp, float* __restrict__ lossp)
{
  if (blockIdx.x == 0 && threadIdx.x == 0) { *flagp = 0u; *lossp = 0.0f; }
  const int row = blockIdx.x * 4 + (threadIdx.x >> 6);   // 0..4095
  const int l = threadIdx.x & 63;
  const int dir = row >> 11, r = row & (NB - 1);
  const float* w  = dir ? w_bw : w_fw;
  const float* mk = dir ? mask_bw : mask_fw;
  float* wit = WiT + (size_t)dir * (NIN * NB);
  float* wsp = Wspk + (size_t)dir * (NSYN * NB);
  u16*   osp = OFFspk + (size_t)dir * (NSYN * NB);
  const u64 ltm = (1ull << l) - 1ull;
  int sc = 0;
#pragma unroll
  for (int ch = 0; ch < 5; ++ch) {
    const int j = ch * 64 + l;
    const float m = (j < KS) ? mk[(size_t)r * KS + j] : 0.0f;
    const u64 bits = __ballot(m != 0.0f);
    const u64 sbits = (ch == 0) ? ((bits >> NIN) << NIN) : bits;  // entries j>=39
    if (ch == 0 && j < NIN) {
      wit[(size_t)j * NB + r] = (m != 0.0f) ? w[(size_t)r * KS + j] : 0.0f;
    } else if (m != 0.0f) {
      const int pos = sc + (int)__popcll(sbits & ltm);
      if (pos < NSYN) {
        wsp[(size_t)pos * NB + r] = w[(size_t)r * KS + j];
        osp[(size_t)pos * NB + r] = (u16)((j - NIN) * 4);
      }
    }
    sc += (int)__popcll(sbits);
  }
  for (int p = sc + l; p < NSYN; p += 64) {   // pad -> permanent-zero slot
    wsp[(size_t)p * NB + r] = 0.0f;
    osp[(size_t)p * NB + r] = (u16)(256 * 4);
  }
  if (l == 0) {
    const float* tn = dir ? tau_n_bw : tau_n_fw;
    const float* bb = dir ? b_bw : b_fw;
    BETA[dir * NB + r]  = 1.0f / (1.0f + expf(-tn[r]));
    CBIAS[dir * NB + r] = bb[r];
    if (r < HID) {
      const float* tm = dir ? tau_m_bw : tau_m_fw;
      ALPHA[dir * HID + r] = 1.0f / (1.0f + expf(-tm[r]));
    }
  }
}

// --------------------------------------------- per-frame input lin (fp16) ----
__global__ __launch_bounds__(512) void lin_gemm(
    const float* __restrict__ x, const float* __restrict__ WiT,
    const float* __restrict__ CBIAS, u16* __restrict__ LINH)
{
  const int bid = blockIdx.x;          // 0..1603
  const int cidx = bid >> 2, bg = bid & 3;
  const int dir = (cidx < 200) ? 0 : 1;
  const int c = (dir == 0) ? cidx : (cidx - 200);
  const int fr = (dir == 0) ? c : ((c == 0) ? 0 : 200 - c);
  const int b0 = bg * 8;
  const int t = threadIdx.x;

  __shared__ float xs[NIN * 8];        // xs[cc*8 + p]
  if (t < NIN * 8) {
    const int cc = t >> 3, p = t & 7;
    xs[t] = x[(size_t)(b0 + p) * (SFRAMES * NIN) + fr * NIN + cc];
  }
  __syncthreads();

  const float* wit = WiT + (size_t)dir * (NIN * NB) + t * 4;
  const float4 bv = *reinterpret_cast<const float4*>(CBIAS + dir * NB + t * 4);
  const float bias4[4] = {bv.x, bv.y, bv.z, bv.w};

  float acc[8][4];
#pragma unroll
  for (int p = 0; p < 8; ++p)
#pragma unroll
    for (int k = 0; k < 4; ++k) acc[p][k] = 0.0f;

#pragma unroll 3
  for (int cc = 0; cc < NIN; ++cc) {
    const float4 wv = *reinterpret_cast<const float4*>(wit + (size_t)cc * NB);
    const float4 s0 = *reinterpret_cast<const float4*>(&xs[cc * 8]);
    const float4 s1 = *reinterpret_cast<const float4*>(&xs[cc * 8 + 4]);
    const float sxa[8] = {s0.x, s0.y, s0.z, s0.w, s1.x, s1.y, s1.z, s1.w};
#pragma unroll
    for (int p = 0; p < 8; ++p) {
      acc[p][0] = fmaf(wv.x, sxa[p], acc[p][0]);
      acc[p][1] = fmaf(wv.y, sxa[p], acc[p][1]);
      acc[p][2] = fmaf(wv.z, sxa[p], acc[p][2]);
      acc[p][3] = fmaf(wv.w, sxa[p], acc[p][3]);
    }
  }

#pragma unroll
  for (int p = 0; p < 8; ++p) {
    u16* dst = LINH + ((size_t)(dir * 32 + b0 + p) * NBLK + c) * NB + t * 4;
    union { u16 h[4]; uint2 u; } pk;
#pragma unroll
    for (int k = 0; k < 4; ++k) {
      const _Float16 hv = (_Float16)(acc[p][k] + bias4[k]);
      pk.h[k] = *reinterpret_cast<const u16*>(&hv);
    }
    *reinterpret_cast<uint2*>(dst) = pk.u;
  }
}

// -------------------------------------------- parallel silent certificate ----
// One thread per (chain, neuron). Replays the scan's fast path with a
// GUARD BAND (fail if mmax > 0.999): es(t) within a window is computed from
// window-start e2 and precomputed beta^t tables (beta-powers reassociation,
// error << 1e-3), so the 10 step-sums have NO cross-step dependency -> pure
// ILP. e2 advances once per window (*= beta^10). If the flag trips for any
// reason, the exact serial scan runs -> correctness never depends on this.
__global__ __launch_bounds__(64, 1) void cert_scan(
    const u16* __restrict__ LINH, const float* __restrict__ BETA,
    const float* __restrict__ ALPHA, u32* __restrict__ flag)
{
  const int bid = blockIdx.x;
  const int chain = bid >> 2;
  const int dir = chain >> 5;
  const int nrn = (bid & 3) * 64 + threadIdx.x;   // 0..255

  v2f e2[4], lold[4];
  v2f bp[10][4];                      // bp[t][i] = beta^(t+1), t=0..9
  {
    const v2f* bpr = reinterpret_cast<const v2f*>(BETA + dir * NB + nrn * 8);
#pragma unroll
    for (int i = 0; i < 4; ++i) {
      bp[0][i] = bpr[i];
      e2[i] = (v2f){0.f, 0.f};
      lold[i] = (v2f){0.f, 0.f};
    }
#pragma unroll
    for (int t = 1; t < 10; ++t)
#pragma unroll
      for (int i = 0; i < 4; ++i) bp[t][i] = bp[t - 1][i] * bp[0][i];
  }
  const float al = ALPHA[dir * HID + nrn];
  const float om = 1.0f - al;

  float SLC = 0.0f, mem = 0.0f, mmax = -1e30f;

  const u16* ap = LINH + (size_t)chain * NBLK * NB + (size_t)nrn * 8;
  auto ld = [&](int k) {
    return *reinterpret_cast<const uint4*>(ap + (size_t)k * NB);
  };
  auto tree8 = [](const v2f v[4]) -> float {
    const v2f a = v[0] + v[1];
    const v2f b = v[2] + v[3];
    const v2f t = a + b;
    return t.x + t.y;
  };
  auto commit = [&](uint4 vn) {
    const _Float16* hn = reinterpret_cast<const _Float16*>(&vn);
    v2f ln2[4];
#pragma unroll
    for (int i = 0; i < 4; ++i) {
      const float fn0 = (float)hn[2 * i], fn1 = (float)hn[2 * i + 1];
      v2f dd; dd.x = lold[i].x - fn0; dd.y = lold[i].y - fn1;
      e2[i] += dd;
      ln2[i].x = fn0; ln2[i].y = fn1;
      lold[i] = ln2[i];
    }
    const float Sl = tree8(ln2);
    SLC = om * Sl;
  };
  // window: 10 independent beta-power dot products (no cross-step dep),
  // one e2 advance by beta^10, then the short serial mem/max chain.
  auto win10 = [&]() {
    float es[10];
#pragma unroll
    for (int t = 0; t < 10; ++t) {
      v2f tmp[4];
#pragma unroll
      for (int i = 0; i < 4; ++i) tmp[i] = e2[i] * bp[t][i];
      es[t] = tree8(tmp);
    }
#pragma unroll
    for (int i = 0; i < 4; ++i) e2[i] *= bp[9][i];
#pragma unroll
    for (int t = 0; t < 10; ++t) {
      mem = fmaf(al, mem, fmaf(om, es[t], SLC));
      mmax = fmaxf(mmax, mem);
    }
  };
  auto win9 = [&]() {
    float es[9];
#pragma unroll
    for (int t = 0; t < 9; ++t) {
      v2f tmp[4];
#pragma unroll
      for (int i = 0; i < 4; ++i) tmp[i] = e2[i] * bp[t][i];
      es[t] = tree8(tmp);
    }
#pragma unroll
    for (int i = 0; i < 4; ++i) e2[i] *= bp[8][i];
#pragma unroll
    for (int t = 0; t < 9; ++t) {
      mem = fmaf(al, mem, fmaf(om, es[t], SLC));
      mmax = fmaxf(mmax, mem);
    }
  };
  auto fstep = [&]() {
#pragma unroll
    for (int i = 0; i < 4; ++i) e2[i] *= bp[0][i];
    const float esum = tree8(e2);
    mem = fmaf(al, mem, fmaf(om, esum, SLC));
    mmax = fmaxf(mmax, mem);
  };

  uint4 p0 = ld(0), p1 = ld(1), p2 = ld(2), p3 = ld(3);

  if (dir == 0) {
    // 200 windows of 10 steps; consumes c0..c199, issues up to c203 (pad)
#pragma unroll 1
    for (int w = 0; w < SFRAMES; w += 4) {
      commit(p0); p0 = ld(w + 4);
      win10();
      commit(p1); p1 = ld(w + 5);
      win10();
      commit(p2); p2 = ld(w + 6);
      win10();
      commit(p3); p3 = ld(w + 7);
      win10();
    }
  } else {
    // segments: c0 x1 step, c1..c199 x10 (as 1 fstep + commit + 9), c200 x(1+9)
    commit(p0); p0 = ld(4);       // c0
    fstep();
    commit(p1); p1 = ld(5);       // c1
    win9();
#pragma unroll 1
    for (int it = 0; it < 49; ++it) {    // commits c2..c197, issues c6..c201
      const int base = 6 + it * 4;
      fstep();
      commit(p2); p2 = ld(base);
      win9();
      fstep();
      commit(p3); p3 = ld(base + 1);
      win9();
      fstep();
      commit(p0); p0 = ld(base + 2);
      win9();
      fstep();
      commit(p1); p1 = ld(base + 3);
      win9();
    }
    // c198 (p2), c199 (p3), c200 (p0); c201 (p1) is pad, never consumed
    fstep();
    commit(p2);
    win9();
    fstep();
    commit(p3);
    win9();
    fstep();
    commit(p0);
    win9();
  }

  const bool fail = (mmax > 0.999f);   // guard band vs exact scan's (mem > 1)
  if (__any(fail ? 1 : 0) && threadIdx.x == 0) atomicOr(flag, 1u);
}

// ------------------------------------------------------- recurrent core ----
__device__ __forceinline__ void gload_lds16(const void* g, void* l) {
  __builtin_amdgcn_global_load_lds(
      (const __attribute__((address_space(1))) void*)g,
      (__attribute__((address_space(3))) void*)l, 16, 0, 0);
}

// grid = 64 chains, block = 64 (ONE wave). Early-exits when certified silent.
// EXACT semantics (reference arithmetic); runs only if the cert flag trips.
__global__ __launch_bounds__(64, 1) void snn_scan(
    const u16* __restrict__ LINH, const float* __restrict__ Wspk,
    const u16* __restrict__ OFFspk, const float* __restrict__ BETA,
    const float* __restrict__ ALPHA, float* __restrict__ FRAMES,
    const u32* __restrict__ flag)
{
  if (*flag == 0u) return;     // certified silent: outputs produced downstream

  const int chain = blockIdx.x;
  const int dir = chain >> 5;
  const int l = threadIdx.x;

  __shared__ __align__(16) u16 ring[4][NB];   // lin fp16 4-slot ring
  __shared__ __align__(16) float spkbuf[260]; // spikes; slots 256..259 stay 0

  {
    const float4 z4 = {0.f, 0.f, 0.f, 0.f};
    *reinterpret_cast<float4*>(&spkbuf[l * 4]) = z4;
    if (l == 0) *reinterpret_cast<float4*>(&spkbuf[256]) = z4;
    const uint4 zu = {0u, 0u, 0u, 0u};
    uint4* zz = reinterpret_cast<uint4*>(&ring[3][l * 32]);   // lin(-1) = 0
    zz[0] = zu; zz[1] = zu; zz[2] = zu; zz[3] = zu;
  }

  v2f e2[4][4], be2[4][4];
  float SLC[4] = {0.f, 0.f, 0.f, 0.f};
  float mem[4] = {0.f, 0.f, 0.f, 0.f};
  float sp[4] = {0.f, 0.f, 0.f, 0.f};
  float al[4], om[4];
#pragma unroll
  for (int q = 0; q < 4; ++q) {
    const v2f* bp = reinterpret_cast<const v2f*>(BETA + dir * NB + l * 32 + q * 8);
#pragma unroll
    for (int i = 0; i < 4; ++i) { be2[q][i] = bp[i]; e2[q][i] = (v2f){0.f, 0.f}; }
    al[q] = ALPHA[dir * HID + l * 4 + q];
    om[q] = 1.0f - al[q];
  }

  const u16* LB = LINH + (size_t)chain * NBLK * NB;
#pragma unroll
  for (int i = 0; i < 4; ++i) {
    gload_lds16(LB + 0 * NB + i * 512 + l * 8, &ring[0][i * 512]);
    gload_lds16(LB + 1 * NB + i * 512 + l * 8, &ring[1][i * 512]);
  }

  const float* wsp = Wspk + (size_t)dir * (NSYN * NB) + l * 32;
  const u16*  ofp = OFFspk + (size_t)dir * (NSYN * NB) + l * 32;
  float* frow = FRAMES + (size_t)chain * (SFRAMES * HID) + l * 4;

  int F = 0, c = 0;
  float mmax[4], facc[4];
  float4 pend = {0.f, 0.f, 0.f, 0.f};

  auto tree8 = [](const v2f v[4]) -> float {
    const v2f a = v[0] + v[1];
    const v2f b = v[2] + v[3];
    const v2f t = a + b;
    return t.x + t.y;
  };

  auto commit = [&](bool dopref) {
    const int sn = c & 3, so = (c + 3) & 3;
#pragma unroll
    for (int q = 0; q < 4; ++q) {
      const uint4 vn = *reinterpret_cast<const uint4*>(&ring[sn][l * 32 + q * 8]);
      const uint4 vo = *reinterpret_cast<const uint4*>(&ring[so][l * 32 + q * 8]);
      const _Float16* hn = reinterpret_cast<const _Float16*>(&vn);
      const _Float16* ho = reinterpret_cast<const _Float16*>(&vo);
      v2f ln2[4];
#pragma unroll
      for (int i = 0; i < 4; ++i) {
        const float fn0 = (float)hn[2 * i], fn1 = (float)hn[2 * i + 1];
        v2f dd; dd.x = (float)ho[2 * i] - fn0; dd.y = (float)ho[2 * i + 1] - fn1;
        e2[q][i] += dd;
        ln2[i].x = fn0; ln2[i].y = fn1;
      }
      const float Sl = tree8(ln2);
      SLC[q] = om[q] * Sl;
    }
    if (dopref) {
      const u16* src = LB + (size_t)(c + 2) * NB;
      u16* dst = &ring[(c + 2) & 3][0];
#pragma unroll
      for (int i = 0; i < 4; ++i)
        gload_lds16(src + i * 512 + l * 8, dst + i * 512);
    }
    ++c;
  };

  auto fstep = [&]() {
#pragma unroll
    for (int q = 0; q < 4; ++q)
#pragma unroll
      for (int i = 0; i < 4; ++i) e2[q][i] *= be2[q][i];
#pragma unroll
    for (int q = 0; q < 4; ++q) {
      const float esum = tree8(e2[q]);
      mem[q] = fmaf(al[q], mem[q], fmaf(om[q], esum, SLC[q]));
      mmax[q] = fmaxf(mmax[q], mem[q]);
    }
  };

  auto sstep = [&]() {
    if (__builtin_expect(F, 0)) {       // spikes live: exact gather
      float scv[4][8];
#pragma unroll
      for (int q = 0; q < 4; ++q)
#pragma unroll
        for (int j = 0; j < 8; ++j) scv[q][j] = 0.0f;
      const char* kb = reinterpret_cast<const char*>(&spkbuf[0]);
#pragma unroll 1
      for (int s = 0; s < NSYN; ++s) {
#pragma unroll
        for (int q = 0; q < 4; ++q) {
          float wv[8];
          *reinterpret_cast<float4*>(&wv[0]) =
              *reinterpret_cast<const float4*>(wsp + (size_t)s * NB + q * 8);
          *reinterpret_cast<float4*>(&wv[4]) =
              *reinterpret_cast<const float4*>(wsp + (size_t)s * NB + q * 8 + 4);
          const uint4 ov = *reinterpret_cast<const uint4*>(ofp + (size_t)s * NB + q * 8);
          const u16* of = reinterpret_cast<const u16*>(&ov);
#pragma unroll
          for (int j = 0; j < 8; ++j)
            scv[q][j] += wv[j] * *reinterpret_cast<const float*>(kb + of[j]);
        }
      }
#pragma unroll
      for (int q = 0; q < 4; ++q)
#pragma unroll
        for (int i = 0; i < 4; ++i) {
          v2f sc2; sc2.x = scv[q][2 * i]; sc2.y = scv[q][2 * i + 1];
          const v2f one = {1.0f, 1.0f};
          e2[q][i] = be2[q][i] * e2[q][i] + (one - be2[q][i]) * sc2;
        }
    } else {                            // silent: identical to fstep core
#pragma unroll
      for (int q = 0; q < 4; ++q)
#pragma unroll
        for (int i = 0; i < 4; ++i) e2[q][i] *= be2[q][i];
    }
    float ssum = 0.0f;
#pragma unroll
    for (int q = 0; q < 4; ++q) {
      const float esum = tree8(e2[q]);
      const float g = fmaf(om[q], esum, SLC[q]);
      mem[q] = fmaf(al[q], mem[q], g - sp[q]);
      sp[q] = (mem[q] > 1.0f) ? 1.0f : 0.0f;
      facc[q] += sp[q];
      ssum += sp[q];
    }
    const float4 sv = {sp[0], sp[1], sp[2], sp[3]};
    *reinterpret_cast<float4*>(&spkbuf[l * 4]) = sv;
    F = __any(ssum > 0.0f);
  };

#pragma unroll 1
  for (int w = 0; w < SFRAMES; ++w) {
    v2f es[4][4]; float SLCs[4], mems_[4], sps[4];
#pragma unroll
    for (int q = 0; q < 4; ++q) {
#pragma unroll
      for (int i = 0; i < 4; ++i) es[q][i] = e2[q][i];
      SLCs[q] = SLC[q]; mems_[q] = mem[q]; sps[q] = sp[q];
    }
    const int cs = c;
    bool slow = (F != 0);
    bool prefed = false;

    if (!slow) {
      prefed = true;
      mmax[0] = mmax[1] = mmax[2] = mmax[3] = -1e30f;
      if (dir == 0) {
        VMW0(); commit(true);
        if (w) *reinterpret_cast<float4*>(frow + (w - 1) * HID) = pend;
#pragma unroll
        for (int t = 0; t < 10; ++t) fstep();
      } else {
        if (w == 0) { VMW0(); commit(true); }
        fstep();
        VMW0(); commit(true);
        if (w) *reinterpret_cast<float4*>(frow + (w - 1) * HID) = pend;
#pragma unroll
        for (int t = 0; t < 9; ++t) fstep();
      }
      const int viol = (mmax[0] > 1.0f) || (mmax[1] > 1.0f) ||
                       (mmax[2] > 1.0f) || (mmax[3] > 1.0f);
      slow = (__any(viol) != 0);
      if (!slow) {
        pend = (float4){0.f, 0.f, 0.f, 0.f};   // facc = 0 exactly
      } else {                                  // restore + redo
#pragma unroll
        for (int q = 0; q < 4; ++q) {
#pragma unroll
          for (int i = 0; i < 4; ++i) e2[q][i] = es[q][i];
          SLC[q] = SLCs[q]; mem[q] = mems_[q]; sp[q] = sps[q];
        }
        c = cs;
      }
    }
    if (slow) {
      facc[0] = facc[1] = facc[2] = facc[3] = 0.0f;
      if (dir == 0) {
        VMW0(); commit(!prefed);
        if (w) *reinterpret_cast<float4*>(frow + (w - 1) * HID) = pend;
#pragma unroll 1
        for (int t = 0; t < 10; ++t) sstep();
      } else {
        if (w == 0) { VMW0(); commit(!prefed); }
        sstep();
        VMW0(); commit(!prefed);
        if (w) *reinterpret_cast<float4*>(frow + (w - 1) * HID) = pend;
#pragma unroll 1
        for (int t = 0; t < 9; ++t) sstep();
      }
      pend = (float4){facc[0] * 0.1f, facc[1] * 0.1f, facc[2] * 0.1f, facc[3] * 0.1f};
    }
  }
  *reinterpret_cast<float4*>(frow + (SFRAMES - 1) * HID) = pend;
}

// ------------------------------------------------------------- readout ----
__global__ __launch_bounds__(256) void ro_matmul(
    const float* __restrict__ FRAMES, const float* __restrict__ w_ro,
    const float* __restrict__ b_ro, float* __restrict__ Y,
    const u32* __restrict__ flag)
{
  if (*flag == 0u) return;   // certified silent: ro_scan uses b_ro directly

  const int bid = blockIdx.x;
  const int s = bid >> 1, b0 = (bid & 1) * 16;
  __shared__ float rowc[16 * 132];
  __shared__ float wlds[48 * 132];
  const int bb = threadIdx.x >> 4;
  const int oc = threadIdx.x & 15;
  const int o1 = oc + 16, o2 = oc + 32;
  float a0 = 0.f, a1 = 0.f, a2 = 0.f;
  const bool u2 = (o2 < OUTC);

#pragma unroll 1
  for (int kc = 0; kc < 4; ++kc) {
    for (int i = threadIdx.x; i < 16 * 128; i += 256) {
      const int rb = i >> 7, kk = i & 127;
      float v;
      if (kc < 2)
        v = FRAMES[((size_t)(b0 + rb) * SFRAMES + s) * HID + kc * 128 + kk];
      else
        v = FRAMES[((size_t)(32 + b0 + rb) * SFRAMES + (199 - s)) * HID + (kc - 2) * 128 + kk];
      rowc[rb * 132 + kk] = v;
    }
    for (int i = threadIdx.x; i < OUTC * 128; i += 256) {
      const int o = i >> 7, kk = i & 127;
      wlds[o * 132 + kk] = w_ro[(size_t)o * 512 + kc * 128 + kk];
    }
    __syncthreads();

    const float* rp = &rowc[bb * 132];
    const float* w0 = &wlds[oc * 132];
    const float* w1 = &wlds[o1 * 132];
    const float* w2 = &wlds[o2 * 132];
#pragma unroll 8
    for (int kk = 0; kk < 128; kk += 4) {
      const float4 a  = *reinterpret_cast<const float4*>(rp + kk);
      const float4 v0 = *reinterpret_cast<const float4*>(w0 + kk);
      const float4 v1 = *reinterpret_cast<const float4*>(w1 + kk);
      const float4 v2 = *reinterpret_cast<const float4*>(w2 + kk);
      a0 = fmaf(a.x, v0.x, fmaf(a.y, v0.y, fmaf(a.z, v0.z, fmaf(a.w, v0.w, a0))));
      a1 = fmaf(a.x, v1.x, fmaf(a.y, v1.y, fmaf(a.z, v1.z, fmaf(a.w, v1.w, a1))));
      if (u2)
        a2 = fmaf(a.x, v2.x, fmaf(a.y, v2.y, fmaf(a.z, v2.z, fmaf(a.w, v2.w, a2))));
    }
    __syncthreads();
  }

  float* yp = Y + ((size_t)s * 32 + b0 + bb) * OUTC;
  yp[oc] = a0 + b_ro[oc];
  yp[o1] = a1 + b_ro[o1];
  if (u2) yp[o2] = a2 + b_ro[o2];
}

__global__ __launch_bounds__(256) void ro_scan(
    const float* __restrict__ Y, const float* __restrict__ tau_ro,
    const float* __restrict__ b_ro, const int* __restrict__ labels,
    float* __restrict__ out, const u32* __restrict__ flag)
{
  const int b = blockIdx.x;
  const int tid = threadIdx.x;
  __shared__ float buf[SFRAMES * 40];
  __shared__ float lsum[256];

  if (*flag == 0u) {
    if (tid < OUTC) {
      const float ar = 1.0f / (1.0f + expf(-tau_ro[tid]));
      const float omr = 1.0f - ar;
      const float z = b_ro[tid];
      float m = 0.0f;
#pragma unroll 4
      for (int s = 0; s < SFRAMES; ++s) {
        m = ar * m + omr * z;
        buf[s * 40 + tid] = m;
      }
    }
  } else {
    for (int i = tid; i < SFRAMES * OUTC; i += 256) {
      const int s = i / OUTC, o = i - s * OUTC;
      buf[s * 40 + o] = Y[((size_t)s * 32 + b) * OUTC + o];
    }
    __syncthreads();
    if (tid < OUTC) {
      const float ar = 1.0f / (1.0f + expf(-tau_ro[tid]));
      const float omr = 1.0f - ar;
      float m = 0.0f;
#pragma unroll 4
      for (int s = 0; s < SFRAMES; ++s) {
        m = ar * m + omr * buf[s * 40 + tid];
        buf[s * 40 + tid] = m;
      }
    }
  }
  __syncthreads();

  float nacc = 0.0f;
  for (int s = tid; s < SFRAMES; s += 256) {
    float mx = -1e30f;
    for (int j = 0; j < OUTC; ++j) mx = fmaxf(mx, buf[s * 40 + j]);
    float se = 0.0f;
    for (int j = 0; j < OUTC; ++j) se += expf(buf[s * 40 + j] - mx);
    const float lse = logf(se);
    float* op = out + ((size_t)s * 32 + b) * OUTC;
    for (int j = 0; j < OUTC; ++j) op[j] = buf[s * 40 + j] - mx - lse;
    const int lab = labels[b * SFRAMES + s];
    nacc += -(buf[s * 40 + lab] - mx - lse);
  }
  lsum[tid] = nacc;
  __syncthreads();
  for (int off = 128; off > 0; off >>= 1) {
    if (tid < off) lsum[tid] += lsum[tid + off];
    __syncthreads();
  }
  if (tid == 0) atomicAdd(out + SFRAMES * 32 * OUTC, lsum[0] * (1.0f / 32.0f));
}

// -------------------------------------------------------------- launch ----
extern "C" void kernel_launch(void* const* d_in, const int* in_sizes, int n_in,
                              void* d_out, int out_size, void* d_ws, size_t ws_size,
                              hipStream_t stream)
{
  const float* x        = (const float*)d_in[0];
  const int*   labels   = (const int*)d_in[1];
  const float* w_fw     = (const float*)d_in[2];
  const float* b_fw     = (const float*)d_in[3];
  const float* tau_m_fw = (const float*)d_in[4];
  const float* tau_n_fw = (const float*)d_in[5];
  const float* mask_fw  = (const float*)d_in[6];
  const float* w_bw     = (const float*)d_in[7];
  const float* b_bw     = (const float*)d_in[8];
  const float* tau_m_bw = (const float*)d_in[9];
  const float* tau_n_bw = (const float*)d_in[10];
  const float* mask_bw  = (const float*)d_in[11];
  const float* w_ro     = (const float*)d_in[12];
  const float* b_ro     = (const float*)d_in[13];
  const float* tau_m_ro = (const float*)d_in[14];
  float* out = (float*)d_out;

  char* ws = (char*)d_ws;
  float* WiT    = (float*)(ws + WS_WIT);
  float* Wspk   = (float*)(ws + WS_WSPK);
  u16*   OFFspk = (u16*)(ws + WS_OFFSPK);
  float* CBIAS  = (float*)(ws + WS_CBIAS);
  float* BETA   = (float*)(ws + WS_BETA);
  float* ALPHA  = (float*)(ws + WS_ALPHA);
  float* FRAMES = (float*)(ws + WS_FRAMES);
  float* Y      = (float*)(ws + WS_Y);
  u16*   LINH   = (u16*)(ws + WS_LINH);
  u32*   FLAG   = (u32*)(ws + WS_FLAG);

  build_tables<<<1024, 256, 0, stream>>>(w_fw, b_fw, tau_n_fw, mask_fw,
                                         w_bw, b_bw, tau_n_bw, mask_bw,
                                         tau_m_fw, tau_m_bw,
                                         WiT, Wspk, OFFspk, CBIAS, BETA, ALPHA,
                                         FLAG, out + SFRAMES * 32 * OUTC);
  lin_gemm<<<1604, 512, 0, stream>>>(x, WiT, CBIAS, LINH);
  cert_scan<<<256, 64, 0, stream>>>(LINH, BETA, ALPHA, FLAG);
  snn_scan<<<64, 64, 0, stream>>>(LINH, Wspk, OFFspk, BETA, ALPHA, FRAMES, FLAG);
  ro_matmul<<<2 * SFRAMES, 256, 0, stream>>>(FRAMES, w_ro, b_ro, Y, FLAG);
  ro_scan<<<32, 256, 0, stream>>>(Y, tau_m_ro, b_ro, labels, out, FLAG);
}